// Round 15
// baseline (983.435 us; speedup 1.0000x reference)
//
#include <hip/hip_runtime.h>
#include <hip/hip_bf16.h>
#include <cmath>

#define N_NODES 50000
#define N_EDGES 800000
#define NODE_DIM 128
#define EDGE_DIM 100
#define EMB_DIM 92
#define N_GRAPHS 256

typedef __attribute__((ext_vector_type(8))) short short8_t;
typedef __attribute__((ext_vector_type(4))) float float4_t;

__device__ __forceinline__ float softplus_f(float v) {
    return v > 20.0f ? v : __logf(1.0f + __expf(v));
}
__device__ __forceinline__ float sigmoid_f(float v) {
    return 1.0f / (1.0f + __expf(-v));
}
__device__ __forceinline__ float bflo(unsigned u) { return __uint_as_float(u << 16); }
__device__ __forceinline__ float bfhi(unsigned u) { return __uint_as_float(u & 0xffff0000u); }
__device__ __forceinline__ float hlo(unsigned u) {
    unsigned short s = (unsigned short)(u & 0xffffu);
    _Float16 h; __builtin_memcpy(&h, &s, 2); return (float)h;
}
__device__ __forceinline__ float hhi(unsigned u) {
    unsigned short s = (unsigned short)(u >> 16);
    _Float16 h; __builtin_memcpy(&h, &s, 2); return (float)h;
}

// ---------------------------------------------------------------- CSR build
__global__ void deg_kernel(const int* __restrict__ ei, int* __restrict__ deg) {
    int e = blockIdx.x * blockDim.x + threadIdx.x;
    if (e >= N_EDGES) return;
    atomicAdd(&deg[ei[N_EDGES + e]], 1);
}

#define SB 1024
__global__ void scan1_kernel(const int* __restrict__ deg, int* __restrict__ rp,
                             int* __restrict__ bsum) {
    __shared__ int buf[SB];
    int b = blockIdx.x, t = threadIdx.x, i = b * SB + t;
    int v = (i < N_NODES) ? deg[i] : 0;
    buf[t] = v;
    __syncthreads();
    for (int off = 1; off < SB; off <<= 1) {
        int a = (t >= off) ? buf[t - off] : 0;
        __syncthreads();
        buf[t] += a;
        __syncthreads();
    }
    if (i < N_NODES) rp[i] = buf[t] - v;
    if (t == SB - 1) bsum[b] = buf[t];
}
__global__ void scan2_kernel(int* __restrict__ bsum, int n) {
    if (threadIdx.x == 0) {
        int s = 0;
        for (int i = 0; i < n; i++) { int v = bsum[i]; bsum[i] = s; s += v; }
    }
}
__global__ void scan3_kernel(int* __restrict__ rp, const int* __restrict__ bsum) {
    int i = blockIdx.x * SB + threadIdx.x;
    if (i < N_NODES) rp[i] += bsum[blockIdx.x];
    if (i == 0) rp[N_NODES] = N_EDGES;
}

// fill: em[e] = (src as float-bits, d) packed -> one 8B meta load per edge later
__global__ void fill_kernel(const int* __restrict__ ei, const float* __restrict__ R,
                            const int* __restrict__ row_ptr, int* __restrict__ cnt2,
                            float2* __restrict__ em) {
    int e = blockIdx.x * blockDim.x + threadIdx.x;
    if (e >= N_EDGES) return;
    int s = ei[e];
    int dst = ei[N_EDGES + e];
    float dx = R[3 * s + 0] - R[3 * dst + 0];
    float dy = R[3 * s + 1] - R[3 * dst + 1];
    float dz = R[3 * s + 2] - R[3 * dst + 2];
    float d = sqrtf(dx * dx + dy * dy + dz * dz);
    int pos = row_ptr[dst] + atomicAdd(&cnt2[dst], 1);
    em[pos] = make_float2(__int_as_float(s), d);
}

// ---------------------------------------------------------------- graph boundaries
__global__ void gb_kernel(const int* __restrict__ batch, int* __restrict__ gs) {
    int i = blockIdx.x * 256 + threadIdx.x;
    if (i > N_NODES) return;
    int b = (i < N_NODES) ? batch[i] : N_GRAPHS;
    int pb = (i == 0) ? -1 : batch[i - 1];
    for (int g = pb + 1; g <= b; g++) gs[g] = i;
}

// ---------------------------------------------------------------- We -> packed bf16 pairs
// Wep[l][k][c] = (bf16 W[256+k][128+c] << 16) | bf16 W[256+k][c]  -> one dword/tap
__global__ void wcvt_kernel(const float* __restrict__ conv_w, unsigned* __restrict__ Wep) {
    int i = blockIdx.x * 256 + threadIdx.x;
    if (i >= 3 * EDGE_DIM * 128) return;
    int l = i / (EDGE_DIM * 128), r = i - l * (EDGE_DIM * 128);
    int k = r >> 7, c = r & 127;
    const float* row = conv_w + (size_t)l * 356 * 256 + (size_t)(256 + k) * 256;
    __hip_bfloat16 lo = (__hip_bfloat16)row[c];
    __hip_bfloat16 hi = (__hip_bfloat16)row[128 + c];
    Wep[i] = ((unsigned)*(unsigned short*)&hi << 16) | (unsigned)*(unsigned short*)&lo;
}

// ---------------------------------------------------------------- W1|W2 -> MFMA B-fragment layout
__global__ void wprep_kernel(const float* __restrict__ conv_w, short* __restrict__ WbB) {
    int idx = blockIdx.x * 256 + threadIdx.x;
    if (idx >= 3 * 4 * 32 * 64 * 8) return;
    int j = idx & 7;
    int lane = (idx >> 3) & 63;
    int nt = (idx >> 9) & 31;
    int kc = (idx >> 14) & 3;
    int l = idx >> 16;
    int k = kc * 32 + (lane >> 4) * 8 + j;
    int nl = lane & 15;
    int row, col;
    if (nt < 16) { row = k; col = nt * 16 + nl; }
    else { row = 128 + k; col = (nt - 16) * 16 + nl; }
    __hip_bfloat16 bv = (__hip_bfloat16)conv_w[(size_t)l * 356 * 256 + (size_t)row * 256 + col];
    WbB[idx] = *(short*)&bv;
}

// ---------------------------------------------------------------- embedding (writes x fp32 + xb bf16)
__global__ void embed_kernel(const int* __restrict__ z, const float* __restrict__ emb,
                             const float* __restrict__ emb_w, const float* __restrict__ emb_b,
                             float* __restrict__ x, __hip_bfloat16* __restrict__ xb) {
    __shared__ float er[EMB_DIM * 8];
    __shared__ int zi[8];
    int base = blockIdx.x * 8;
    int t = threadIdx.x;  // 0..127
    if (t < 8) zi[t] = z[base + t];
    __syncthreads();
    for (int idx = t; idx < EMB_DIM * 8; idx += 128) {
        int k = idx >> 3, j = idx & 7;
        er[idx] = emb[zi[j] * EMB_DIM + k];
    }
    __syncthreads();
    float acc[8];
    float bb = emb_b[t];
#pragma unroll
    for (int j = 0; j < 8; j++) acc[j] = bb;
    for (int k = 0; k < EMB_DIM; k++) {
        float w = emb_w[k * NODE_DIM + t];
        float4 ja = *(const float4*)&er[k * 8];
        float4 jb = *(const float4*)&er[k * 8 + 4];
        acc[0] = fmaf(w, ja.x, acc[0]); acc[1] = fmaf(w, ja.y, acc[1]);
        acc[2] = fmaf(w, ja.z, acc[2]); acc[3] = fmaf(w, ja.w, acc[3]);
        acc[4] = fmaf(w, jb.x, acc[4]); acc[5] = fmaf(w, jb.y, acc[5]);
        acc[6] = fmaf(w, jb.z, acc[6]); acc[7] = fmaf(w, jb.w, acc[7]);
    }
#pragma unroll
    for (int j = 0; j < 8; j++) {
        x[(base + j) * NODE_DIM + t] = acc[j];
        xb[(base + j) * NODE_DIM + t] = (__hip_bfloat16)acc[j];
    }
}

// ---------------------------------------------------------------- node GEMM via MFMA
// P1 packed fp32 pairs (read once/node); P2 packed FP16 pairs (gathered per edge).
__global__ __launch_bounds__(256) void node_mfma_kernel(
    const __hip_bfloat16* __restrict__ xb, const short* __restrict__ WbB,
    const float* __restrict__ bl, float* __restrict__ P1f, _Float16* __restrict__ P2h) {
    int t = threadIdx.x;
    int wv = t >> 6, lane = t & 63;
    int mrow = lane & 15, q = lane >> 4;
    int base = blockIdx.x * 16;
    const short* xr = (const short*)xb + (size_t)(base + mrow) * 128 + q * 8;
    float4_t acc[8];
#pragma unroll
    for (int i = 0; i < 8; i++) acc[i] = (float4_t){0.f, 0.f, 0.f, 0.f};
#pragma unroll
    for (int kc = 0; kc < 4; kc++) {
        short8_t a = *(const short8_t*)(xr + kc * 32);
#pragma unroll
        for (int i = 0; i < 8; i++) {
            int nt = wv * 8 + i;
            short8_t b = *(const short8_t*)&WbB[((size_t)(kc * 32 + nt) * 64 + lane) * 8];
            acc[i] = __builtin_amdgcn_mfma_f32_16x16x32_bf16(a, b, acc[i], 0, 0, 0);
        }
    }
    // D layout: col = lane&15, row = (lane>>4)*4 + reg
#pragma unroll
    for (int i = 0; i < 8; i++) {
        int nt = wv * 8 + i;
        int np = nt * 16 + mrow;
        if (np < 256) {
            float bb = bl[np];
            int off = 2 * (np & 127) + (np >> 7);
#pragma unroll
            for (int r = 0; r < 4; r++)
                P1f[(size_t)(base + q * 4 + r) * 256 + off] = acc[i][r] + bb;
        } else {
            int np2 = np - 256;
            int off = 2 * (np2 & 127) + (np2 >> 7);
#pragma unroll
            for (int r = 0; r < 4; r++)
                P2h[(size_t)(base + q * 4 + r) * 256 + off] = (_Float16)acc[i][r];
        }
    }
}

// ---------------------------------------------------------------- edge msg v22: v21 pipeline @ 1024-thread blocks
// v21 post-mortem: 512-thr blocks reached only ~1.2-1.5 blocks/CU (occ 30%, not
// the predicted 3-block 75%) -- consistent with coarse LDS allocation granularity
// (51200B rounding toward 64KB -> 2-block cap) plus tail. v22: 1024 threads = 16
// waves share ONE WeL copy. Under ANY granularity hypothesis the ceiling is now
// the 32-waves/CU hardware cap (2 blocks x 102-128KB fits 160KB); even 1 block =
// 50% >> today's 30%. VGPR 60 x 8 waves/SIMD = 480 <= 512. Grid 3125. Everything
// else byte-identical to v21 -- final A/B on wave residency.
#define NTAP 10
__global__ __launch_bounds__(1024) void node_edge_ln_kernel(
    const int* __restrict__ row_ptr, const float2* __restrict__ em,
    const float4* __restrict__ P1v, const uint2* __restrict__ P2q,
    const unsigned* __restrict__ Wep,
    const float* __restrict__ lg, const float* __restrict__ lb,
    float* __restrict__ x, __hip_bfloat16* __restrict__ xb) {
    __shared__ unsigned WeL[EDGE_DIM * 128];  // 51200 B
    {
        const uint4* s4 = (const uint4*)Wep;
        uint4* d4 = (uint4*)WeL;
        for (int i = threadIdx.x; i < EDGE_DIM * 32; i += 1024) d4[i] = s4[i];
    }
    __syncthreads();
    const uint2* WeL2 = (const uint2*)WeL;
    const float sp_ = 6.0f / 99.0f;
    const float inv_s = 99.0f / 6.0f;
    const float coeff = -0.5f * inv_s * inv_s;
    int node = blockIdx.x * 16 + (threadIdx.x >> 6);
    int l = threadIdx.x & 63;
    int e0 = __builtin_amdgcn_readfirstlane(row_ptr[node]);
    int e1 = __builtin_amdgcn_readfirstlane(row_ptr[node + 1]);
    float4 a = P1v[(size_t)node * 64 + l];   // (z1[2l],z2[2l],z1[2l+1],z2[2l+1])
    float2 xv = *(const float2*)&x[(size_t)node * 128 + 2 * l];  // prefetched for LN
    float2 gg = *(const float2*)&lg[2 * l];
    float2 bv = *(const float2*)&lb[2 * l];
    float acc0 = 0.f, acc1 = 0.f;

    if (e0 < e1) {
        const int emax = e1 - 1;
        float2 mA0, mA1, mA2, mA3, mA4, mA5, mA6, mA7;
        float2 mB0, mB1, mB2, mB3, mB4, mB5, mB6, mB7;
        int sA0, sA1, sA2, sA3, sA4, sA5, sA6, sA7;
        int sB0, sB1, sB2, sB3, sB4, sB5, sB6, sB7;
        float dA0, dA1, dA2, dA3, dA4, dA5, dA6, dA7;
        float dB0, dB1, dB2, dB3, dB4, dB5, dB6, dB7;
        uint2 rA0, rA1, rA2, rA3, rA4, rA5, rA6, rA7;
        uint2 rB0, rB1, rB2, rB3, rB4, rB5, rB6, rB7;

#define MISSUE(X, base_)                                                      \
        m##X##0 = em[min((base_) + 0, emax)];                                 \
        m##X##1 = em[min((base_) + 1, emax)];                                 \
        m##X##2 = em[min((base_) + 2, emax)];                                 \
        m##X##3 = em[min((base_) + 3, emax)];                                 \
        m##X##4 = em[min((base_) + 4, emax)];                                 \
        m##X##5 = em[min((base_) + 5, emax)];                                 \
        m##X##6 = em[min((base_) + 6, emax)];                                 \
        m##X##7 = em[min((base_) + 7, emax)];

#define SCAL1(X, j)                                                           \
        s##X##j = __builtin_amdgcn_readfirstlane(__float_as_int(m##X##j.x));  \
        d##X##j = __int_as_float(__builtin_amdgcn_readfirstlane(__float_as_int(m##X##j.y)));

#define SCALARIZE(X)                                                          \
        SCAL1(X, 0) SCAL1(X, 1) SCAL1(X, 2) SCAL1(X, 3)                       \
        SCAL1(X, 4) SCAL1(X, 5) SCAL1(X, 6) SCAL1(X, 7)

#define RISSUE(X)                                                             \
        r##X##0 = P2q[(size_t)s##X##0 * 64 + l];                              \
        r##X##1 = P2q[(size_t)s##X##1 * 64 + l];                              \
        r##X##2 = P2q[(size_t)s##X##2 * 64 + l];                              \
        r##X##3 = P2q[(size_t)s##X##3 * 64 + l];                              \
        r##X##4 = P2q[(size_t)s##X##4 * 64 + l];                              \
        r##X##5 = P2q[(size_t)s##X##5 * 64 + l];                              \
        r##X##6 = P2q[(size_t)s##X##6 * 64 + l];                              \
        r##X##7 = P2q[(size_t)s##X##7 * 64 + l];

#define EMSG(rr, dd, idx_)                                                    \
        if ((idx_) < e1) {                                                    \
            float z10 = a.x + hlo((rr).x), z20 = a.y + hhi((rr).x);           \
            float z11 = a.z + hlo((rr).y), z21 = a.w + hhi((rr).y);           \
            if ((dd) <= 6.34f) {                                              \
                int k0 = max(0, min(EDGE_DIM - NTAP, (int)ceilf((dd) * inv_s - 4.5f))); \
                const uint2* wr = WeL2 + k0 * 64 + l;                         \
                _Pragma("unroll")                                             \
                for (int t_ = 0; t_ < NTAP; t_++) {                           \
                    uint2 u = wr[t_ * 64];                                    \
                    float df = (dd) - (float)(k0 + t_) * sp_;                 \
                    float ee = __expf(coeff * df * df);                       \
                    z10 = fmaf(bflo(u.x), ee, z10); z20 = fmaf(bfhi(u.x), ee, z20); \
                    z11 = fmaf(bflo(u.y), ee, z11); z21 = fmaf(bfhi(u.y), ee, z21); \
                }                                                             \
            }                                                                 \
            acc0 += sigmoid_f(z10) * softplus_f(z20);                         \
            acc1 += sigmoid_f(z11) * softplus_f(z21);                         \
        }

#define COMPUTE(X, eb_)                                                       \
        EMSG(r##X##0, d##X##0, (eb_) + 0) EMSG(r##X##1, d##X##1, (eb_) + 1)   \
        EMSG(r##X##2, d##X##2, (eb_) + 2) EMSG(r##X##3, d##X##3, (eb_) + 3)   \
        EMSG(r##X##4, d##X##4, (eb_) + 4) EMSG(r##X##5, d##X##5, (eb_) + 5)   \
        EMSG(r##X##6, d##X##6, (eb_) + 6) EMSG(r##X##7, d##X##7, (eb_) + 7)

        // prologue: meta b0,b1 in flight; rows b0 issued
        MISSUE(A, e0)
        MISSUE(B, e0 + 8)
        __builtin_amdgcn_sched_barrier(0);
        SCALARIZE(A)
        RISSUE(A)
        __builtin_amdgcn_sched_barrier(0);
        int eb = e0;
        while (true) {
            // phase 1: compute b(k) from rA; prepare b(k+1) rows in rB; meta b(k+2) -> mA
            MISSUE(A, eb + 16)
            __builtin_amdgcn_sched_barrier(0);
            SCALARIZE(B)
            RISSUE(B)
            __builtin_amdgcn_sched_barrier(0);
            COMPUTE(A, eb)
            eb += 8; if (eb >= e1) break;
            // phase 2: mirror
            MISSUE(B, eb + 16)
            __builtin_amdgcn_sched_barrier(0);
            SCALARIZE(A)
            RISSUE(A)
            __builtin_amdgcn_sched_barrier(0);
            COMPUTE(B, eb)
            eb += 8; if (eb >= e1) break;
        }
#undef MISSUE
#undef SCAL1
#undef SCALARIZE
#undef RISSUE
#undef EMSG
#undef COMPUTE
    }

    // ---- fused layernorm + residual + softplus (wave-local) ----
    float s1 = acc0 + acc1;
    float s2 = acc0 * acc0 + acc1 * acc1;
#pragma unroll
    for (int off = 32; off > 0; off >>= 1) {
        s1 += __shfl_xor(s1, off);
        s2 += __shfl_xor(s2, off);
    }
    float mu = s1 * (1.0f / 128.0f);
    float var = s2 * (1.0f / 128.0f) - mu * mu;
    float rstd = rsqrtf(fmaxf(var, 0.f) + 1e-5f);
    float r0 = softplus_f((acc0 - mu) * rstd * gg.x + bv.x + xv.x);
    float r1 = softplus_f((acc1 - mu) * rstd * gg.y + bv.y + xv.y);
    *(float2*)&x[(size_t)node * 128 + 2 * l] = make_float2(r0, r1);
    __hip_bfloat16 h0 = (__hip_bfloat16)r0, h1 = (__hip_bfloat16)r1;
    unsigned pk = ((unsigned)*(unsigned short*)&h1 << 16) | (unsigned)*(unsigned short*)&h0;
    *(unsigned*)&xb[(size_t)node * 128 + 2 * l] = pk;
}

// ---------------------------------------------------------------- fused mean-pool + MLP head
__global__ void pool_head_kernel(const float* __restrict__ x, const int* __restrict__ gs,
                                 const float* __restrict__ cfc_w, const float* __restrict__ cfc_b,
                                 const float* __restrict__ fc_w, const float* __restrict__ fc_b,
                                 const float* __restrict__ out_w, const float* __restrict__ out_b,
                                 float* __restrict__ out) {
    int g = blockIdx.x, c = threadIdx.x;  // 128 threads
    int n0 = gs[g], n1 = gs[g + 1];
    float s = 0.f;
    for (int n = n0; n < n1; n++) s += x[(size_t)n * 128 + c];
    __shared__ float h[128], h2[128];
    h[c] = s / fmaxf((float)(n1 - n0), 1.0f);
    __syncthreads();
    float acc = cfc_b[c];
    for (int k = 0; k < 128; k++) acc = fmaf(h[k], cfc_w[k * 128 + c], acc);
    h2[c] = softplus_f(acc);
    __syncthreads();
    for (int l = 0; l < 2; l++) {
        const float* W = fc_w + l * 128 * 128;
        acc = fc_b[l * 128 + c];
        for (int k = 0; k < 128; k++) acc = fmaf(h2[k], W[k * 128 + c], acc);
        __syncthreads();
        h2[c] = softplus_f(acc);
        __syncthreads();
    }
    h[c] = h2[c] * out_w[c];
    __syncthreads();
    for (int off = 64; off > 0; off >>= 1) {
        if (c < off) h[c] += h[c + off];
        __syncthreads();
    }
    if (c == 0) out[g] = h[0] + out_b[0];
}

// ---------------------------------------------------------------- launcher
extern "C" void kernel_launch(void* const* d_in, const int* in_sizes, int n_in,
                              void* d_out, int out_size, void* d_ws, size_t ws_size,
                              hipStream_t stream) {
    const int*   z      = (const int*)d_in[0];
    const float* R      = (const float*)d_in[1];
    const int*   ei     = (const int*)d_in[2];
    const int*   batch  = (const int*)d_in[3];
    const float* emb    = (const float*)d_in[4];
    const float* emb_w  = (const float*)d_in[5];
    const float* emb_b  = (const float*)d_in[6];
    const float* conv_w = (const float*)d_in[7];
    const float* conv_b = (const float*)d_in[8];
    const float* ln_g   = (const float*)d_in[9];
    const float* ln_b   = (const float*)d_in[10];
    const float* cfc_w  = (const float*)d_in[11];
    const float* cfc_b  = (const float*)d_in[12];
    const float* fc_w   = (const float*)d_in[13];
    const float* fc_b   = (const float*)d_in[14];
    const float* out_w  = (const float*)d_in[15];
    const float* out_b  = (const float*)d_in[16];
    float* out = (float*)d_out;

    float* ws    = (float*)d_ws;
    float* x     = ws;                     // 6,400,000 floats
    float* agg   = x + 6400000;            // 6,400,000 (unused; layout kept)
    float* P1f   = agg + 6400000;          // 12,800,000 (packed fp32 pairs)
    _Float16* P2h = (_Float16*)(P1f + 12800000);  // 12,800,000 halves
    float* emf   = (float*)(P2h + 12800000);      // 1,600,000 (em float2)
    int* s_dst   = (int*)(emf + 1600000);  // 800,000 (unused; layout kept)
    int* row_ptr = s_dst + 800000;         // 50,004
    int* deg     = row_ptr + 50004;        // 50,000
    int* cnt2    = deg + 50000;            // 50,000
    int* bsum    = cnt2 + 50000;           // 64
    int* gs      = bsum + 64;              // 260
    unsigned* Wep        = (unsigned*)(gs + 260);              // 38,400 uints (packed We)
    short* WbB           = (short*)(Wep + 38400);              // 196,608 shorts
    __hip_bfloat16* xb   = (__hip_bfloat16*)(WbB + 196608);    // 6,400,000 bf16
    float2* em = (float2*)emf;

    hipMemsetAsync(deg, 0, (size_t)100000 * 4, stream);  // deg + cnt2
    deg_kernel<<<(N_EDGES + 255) / 256, 256, 0, stream>>>(ei, deg);
    int nsb = (N_NODES + SB - 1) / SB;  // 49
    scan1_kernel<<<nsb, SB, 0, stream>>>(deg, row_ptr, bsum);
    scan2_kernel<<<1, 64, 0, stream>>>(bsum, nsb);
    scan3_kernel<<<nsb, SB, 0, stream>>>(row_ptr, bsum);
    fill_kernel<<<(N_EDGES + 255) / 256, 256, 0, stream>>>(ei, R, row_ptr, cnt2, em);
    gb_kernel<<<(N_NODES + 256) / 256 + 1, 256, 0, stream>>>(batch, gs);
    wcvt_kernel<<<(3 * EDGE_DIM * 128 + 255) / 256, 256, 0, stream>>>(conv_w, Wep);
    wprep_kernel<<<(3 * 4 * 32 * 64 * 8 + 255) / 256, 256, 0, stream>>>(conv_w, WbB);

    embed_kernel<<<N_NODES / 8, 128, 0, stream>>>(z, emb, emb_w, emb_b, x, xb);
    for (int l = 0; l < 3; l++) {
        node_mfma_kernel<<<N_NODES / 16, 256, 0, stream>>>(xb, WbB + (size_t)l * 65536,
                                                           conv_b + l * 256, P1f, P2h);
        node_edge_ln_kernel<<<N_NODES / 16, 1024, 0, stream>>>(
            row_ptr, em, (const float4*)P1f, (const uint2*)P2h,
            Wep + (size_t)l * EDGE_DIM * 128,
            ln_g + l * 128, ln_b + l * 128, x, xb);
    }
    pool_head_kernel<<<N_GRAPHS, 128, 0, stream>>>(x, gs, cfc_w, cfc_b, fc_w, fc_b,
                                                   out_w, out_b, out);
}

// Round 16
// 874.588 us; speedup vs baseline: 1.1245x; 1.1245x over previous
//
#include <hip/hip_runtime.h>
#include <hip/hip_bf16.h>
#include <cmath>

#define N_NODES 50000
#define N_EDGES 800000
#define NODE_DIM 128
#define EDGE_DIM 100
#define EMB_DIM 92
#define N_GRAPHS 256

typedef __attribute__((ext_vector_type(8))) short short8_t;
typedef __attribute__((ext_vector_type(4))) float float4_t;

__device__ __forceinline__ float softplus_f(float v) {
    return v > 20.0f ? v : __logf(1.0f + __expf(v));
}
__device__ __forceinline__ float sigmoid_f(float v) {
    return 1.0f / (1.0f + __expf(-v));
}
__device__ __forceinline__ float bflo(unsigned u) { return __uint_as_float(u << 16); }
__device__ __forceinline__ float bfhi(unsigned u) { return __uint_as_float(u & 0xffff0000u); }
__device__ __forceinline__ float hlo(unsigned u) {
    unsigned short s = (unsigned short)(u & 0xffffu);
    _Float16 h; __builtin_memcpy(&h, &s, 2); return (float)h;
}
__device__ __forceinline__ float hhi(unsigned u) {
    unsigned short s = (unsigned short)(u >> 16);
    _Float16 h; __builtin_memcpy(&h, &s, 2); return (float)h;
}

// ---------------------------------------------------------------- CSR build
__global__ void deg_kernel(const int* __restrict__ ei, int* __restrict__ deg) {
    int e = blockIdx.x * blockDim.x + threadIdx.x;
    if (e >= N_EDGES) return;
    atomicAdd(&deg[ei[N_EDGES + e]], 1);
}

#define SB 1024
__global__ void scan1_kernel(const int* __restrict__ deg, int* __restrict__ rp,
                             int* __restrict__ bsum) {
    __shared__ int buf[SB];
    int b = blockIdx.x, t = threadIdx.x, i = b * SB + t;
    int v = (i < N_NODES) ? deg[i] : 0;
    buf[t] = v;
    __syncthreads();
    for (int off = 1; off < SB; off <<= 1) {
        int a = (t >= off) ? buf[t - off] : 0;
        __syncthreads();
        buf[t] += a;
        __syncthreads();
    }
    if (i < N_NODES) rp[i] = buf[t] - v;
    if (t == SB - 1) bsum[b] = buf[t];
}
__global__ void scan2_kernel(int* __restrict__ bsum, int n) {
    if (threadIdx.x == 0) {
        int s = 0;
        for (int i = 0; i < n; i++) { int v = bsum[i]; bsum[i] = s; s += v; }
    }
}
__global__ void scan3_kernel(int* __restrict__ rp, const int* __restrict__ bsum) {
    int i = blockIdx.x * SB + threadIdx.x;
    if (i < N_NODES) rp[i] += bsum[blockIdx.x];
    if (i == 0) rp[N_NODES] = N_EDGES;
}

// fill: em[e] = (src as float-bits, d) packed -> one 8B meta load per edge later
__global__ void fill_kernel(const int* __restrict__ ei, const float* __restrict__ R,
                            const int* __restrict__ row_ptr, int* __restrict__ cnt2,
                            float2* __restrict__ em) {
    int e = blockIdx.x * blockDim.x + threadIdx.x;
    if (e >= N_EDGES) return;
    int s = ei[e];
    int dst = ei[N_EDGES + e];
    float dx = R[3 * s + 0] - R[3 * dst + 0];
    float dy = R[3 * s + 1] - R[3 * dst + 1];
    float dz = R[3 * s + 2] - R[3 * dst + 2];
    float d = sqrtf(dx * dx + dy * dy + dz * dz);
    int pos = row_ptr[dst] + atomicAdd(&cnt2[dst], 1);
    em[pos] = make_float2(__int_as_float(s), d);
}

// ---------------------------------------------------------------- graph boundaries
__global__ void gb_kernel(const int* __restrict__ batch, int* __restrict__ gs) {
    int i = blockIdx.x * 256 + threadIdx.x;
    if (i > N_NODES) return;
    int b = (i < N_NODES) ? batch[i] : N_GRAPHS;
    int pb = (i == 0) ? -1 : batch[i - 1];
    for (int g = pb + 1; g <= b; g++) gs[g] = i;
}

// ---------------------------------------------------------------- We -> packed bf16 pairs
// Wep[l][k][c] = (bf16 W[256+k][128+c] << 16) | bf16 W[256+k][c]  -> one dword/tap
__global__ void wcvt_kernel(const float* __restrict__ conv_w, unsigned* __restrict__ Wep) {
    int i = blockIdx.x * 256 + threadIdx.x;
    if (i >= 3 * EDGE_DIM * 128) return;
    int l = i / (EDGE_DIM * 128), r = i - l * (EDGE_DIM * 128);
    int k = r >> 7, c = r & 127;
    const float* row = conv_w + (size_t)l * 356 * 256 + (size_t)(256 + k) * 256;
    __hip_bfloat16 lo = (__hip_bfloat16)row[c];
    __hip_bfloat16 hi = (__hip_bfloat16)row[128 + c];
    Wep[i] = ((unsigned)*(unsigned short*)&hi << 16) | (unsigned)*(unsigned short*)&lo;
}

// ---------------------------------------------------------------- W1|W2 -> MFMA B-fragment layout
__global__ void wprep_kernel(const float* __restrict__ conv_w, short* __restrict__ WbB) {
    int idx = blockIdx.x * 256 + threadIdx.x;
    if (idx >= 3 * 4 * 32 * 64 * 8) return;
    int j = idx & 7;
    int lane = (idx >> 3) & 63;
    int nt = (idx >> 9) & 31;
    int kc = (idx >> 14) & 3;
    int l = idx >> 16;
    int k = kc * 32 + (lane >> 4) * 8 + j;
    int nl = lane & 15;
    int row, col;
    if (nt < 16) { row = k; col = nt * 16 + nl; }
    else { row = 128 + k; col = (nt - 16) * 16 + nl; }
    __hip_bfloat16 bv = (__hip_bfloat16)conv_w[(size_t)l * 356 * 256 + (size_t)row * 256 + col];
    WbB[idx] = *(short*)&bv;
}

// ---------------------------------------------------------------- embedding (writes x fp32 + xb bf16)
__global__ void embed_kernel(const int* __restrict__ z, const float* __restrict__ emb,
                             const float* __restrict__ emb_w, const float* __restrict__ emb_b,
                             float* __restrict__ x, __hip_bfloat16* __restrict__ xb) {
    __shared__ float er[EMB_DIM * 8];
    __shared__ int zi[8];
    int base = blockIdx.x * 8;
    int t = threadIdx.x;  // 0..127
    if (t < 8) zi[t] = z[base + t];
    __syncthreads();
    for (int idx = t; idx < EMB_DIM * 8; idx += 128) {
        int k = idx >> 3, j = idx & 7;
        er[idx] = emb[zi[j] * EMB_DIM + k];
    }
    __syncthreads();
    float acc[8];
    float bb = emb_b[t];
#pragma unroll
    for (int j = 0; j < 8; j++) acc[j] = bb;
    for (int k = 0; k < EMB_DIM; k++) {
        float w = emb_w[k * NODE_DIM + t];
        float4 ja = *(const float4*)&er[k * 8];
        float4 jb = *(const float4*)&er[k * 8 + 4];
        acc[0] = fmaf(w, ja.x, acc[0]); acc[1] = fmaf(w, ja.y, acc[1]);
        acc[2] = fmaf(w, ja.z, acc[2]); acc[3] = fmaf(w, ja.w, acc[3]);
        acc[4] = fmaf(w, jb.x, acc[4]); acc[5] = fmaf(w, jb.y, acc[5]);
        acc[6] = fmaf(w, jb.z, acc[6]); acc[7] = fmaf(w, jb.w, acc[7]);
    }
#pragma unroll
    for (int j = 0; j < 8; j++) {
        x[(base + j) * NODE_DIM + t] = acc[j];
        xb[(base + j) * NODE_DIM + t] = (__hip_bfloat16)acc[j];
    }
}

// ---------------------------------------------------------------- node GEMM via MFMA
// P1 packed fp32 pairs (read once/node); P2 packed FP16 pairs (gathered per edge).
__global__ __launch_bounds__(256) void node_mfma_kernel(
    const __hip_bfloat16* __restrict__ xb, const short* __restrict__ WbB,
    const float* __restrict__ bl, float* __restrict__ P1f, _Float16* __restrict__ P2h) {
    int t = threadIdx.x;
    int wv = t >> 6, lane = t & 63;
    int mrow = lane & 15, q = lane >> 4;
    int base = blockIdx.x * 16;
    const short* xr = (const short*)xb + (size_t)(base + mrow) * 128 + q * 8;
    float4_t acc[8];
#pragma unroll
    for (int i = 0; i < 8; i++) acc[i] = (float4_t){0.f, 0.f, 0.f, 0.f};
#pragma unroll
    for (int kc = 0; kc < 4; kc++) {
        short8_t a = *(const short8_t*)(xr + kc * 32);
#pragma unroll
        for (int i = 0; i < 8; i++) {
            int nt = wv * 8 + i;
            short8_t b = *(const short8_t*)&WbB[((size_t)(kc * 32 + nt) * 64 + lane) * 8];
            acc[i] = __builtin_amdgcn_mfma_f32_16x16x32_bf16(a, b, acc[i], 0, 0, 0);
        }
    }
    // D layout: col = lane&15, row = (lane>>4)*4 + reg
#pragma unroll
    for (int i = 0; i < 8; i++) {
        int nt = wv * 8 + i;
        int np = nt * 16 + mrow;
        if (np < 256) {
            float bb = bl[np];
            int off = 2 * (np & 127) + (np >> 7);
#pragma unroll
            for (int r = 0; r < 4; r++)
                P1f[(size_t)(base + q * 4 + r) * 256 + off] = acc[i][r] + bb;
        } else {
            int np2 = np - 256;
            int off = 2 * (np2 & 127) + (np2 >> 7);
#pragma unroll
            for (int r = 0; r < 4; r++)
                P2h[(size_t)(base + q * 4 + r) * 256 + off] = (_Float16)acc[i][r];
        }
    }
}

// ---------------------------------------------------------------- edge msg v23 (= v21, proven best):
// FIFO-safe batch-8 pipeline @ 512-thread blocks. v22 (1024-thr) falsified the
// residency lever: occupancy stayed 27% and dur regressed 190->225 (16 waves
// serialize on one WeL staging barrier; coarser scheduling). Final model: the
// edge kernel is bound by the device random-row gather service rate (~2.1 TB/s
// for 512B rows; 800K rows / 190us = 4.2 rows/ns), invariant across bytes/2,
// requests/2, occ 27-73%, chains x2, lanes x4, FIFO depth 8, waves x2/x4.
// v21 is the best measured operating point (875us end-to-end); revert to it.
#define NTAP 10
__global__ __launch_bounds__(512) void node_edge_ln_kernel(
    const int* __restrict__ row_ptr, const float2* __restrict__ em,
    const float4* __restrict__ P1v, const uint2* __restrict__ P2q,
    const unsigned* __restrict__ Wep,
    const float* __restrict__ lg, const float* __restrict__ lb,
    float* __restrict__ x, __hip_bfloat16* __restrict__ xb) {
    __shared__ unsigned WeL[EDGE_DIM * 128];  // 51200 B
    {
        const uint4* s4 = (const uint4*)Wep;
        uint4* d4 = (uint4*)WeL;
        for (int i = threadIdx.x; i < EDGE_DIM * 32; i += 512) d4[i] = s4[i];
    }
    __syncthreads();
    const uint2* WeL2 = (const uint2*)WeL;
    const float sp_ = 6.0f / 99.0f;
    const float inv_s = 99.0f / 6.0f;
    const float coeff = -0.5f * inv_s * inv_s;
    int node = blockIdx.x * 8 + (threadIdx.x >> 6);
    int l = threadIdx.x & 63;
    int e0 = __builtin_amdgcn_readfirstlane(row_ptr[node]);
    int e1 = __builtin_amdgcn_readfirstlane(row_ptr[node + 1]);
    float4 a = P1v[(size_t)node * 64 + l];   // (z1[2l],z2[2l],z1[2l+1],z2[2l+1])
    float2 xv = *(const float2*)&x[(size_t)node * 128 + 2 * l];  // prefetched for LN
    float2 gg = *(const float2*)&lg[2 * l];
    float2 bv = *(const float2*)&lb[2 * l];
    float acc0 = 0.f, acc1 = 0.f;

    if (e0 < e1) {
        const int emax = e1 - 1;
        float2 mA0, mA1, mA2, mA3, mA4, mA5, mA6, mA7;
        float2 mB0, mB1, mB2, mB3, mB4, mB5, mB6, mB7;
        int sA0, sA1, sA2, sA3, sA4, sA5, sA6, sA7;
        int sB0, sB1, sB2, sB3, sB4, sB5, sB6, sB7;
        float dA0, dA1, dA2, dA3, dA4, dA5, dA6, dA7;
        float dB0, dB1, dB2, dB3, dB4, dB5, dB6, dB7;
        uint2 rA0, rA1, rA2, rA3, rA4, rA5, rA6, rA7;
        uint2 rB0, rB1, rB2, rB3, rB4, rB5, rB6, rB7;

#define MISSUE(X, base_)                                                      \
        m##X##0 = em[min((base_) + 0, emax)];                                 \
        m##X##1 = em[min((base_) + 1, emax)];                                 \
        m##X##2 = em[min((base_) + 2, emax)];                                 \
        m##X##3 = em[min((base_) + 3, emax)];                                 \
        m##X##4 = em[min((base_) + 4, emax)];                                 \
        m##X##5 = em[min((base_) + 5, emax)];                                 \
        m##X##6 = em[min((base_) + 6, emax)];                                 \
        m##X##7 = em[min((base_) + 7, emax)];

#define SCAL1(X, j)                                                           \
        s##X##j = __builtin_amdgcn_readfirstlane(__float_as_int(m##X##j.x));  \
        d##X##j = __int_as_float(__builtin_amdgcn_readfirstlane(__float_as_int(m##X##j.y)));

#define SCALARIZE(X)                                                          \
        SCAL1(X, 0) SCAL1(X, 1) SCAL1(X, 2) SCAL1(X, 3)                       \
        SCAL1(X, 4) SCAL1(X, 5) SCAL1(X, 6) SCAL1(X, 7)

#define RISSUE(X)                                                             \
        r##X##0 = P2q[(size_t)s##X##0 * 64 + l];                              \
        r##X##1 = P2q[(size_t)s##X##1 * 64 + l];                              \
        r##X##2 = P2q[(size_t)s##X##2 * 64 + l];                              \
        r##X##3 = P2q[(size_t)s##X##3 * 64 + l];                              \
        r##X##4 = P2q[(size_t)s##X##4 * 64 + l];                              \
        r##X##5 = P2q[(size_t)s##X##5 * 64 + l];                              \
        r##X##6 = P2q[(size_t)s##X##6 * 64 + l];                              \
        r##X##7 = P2q[(size_t)s##X##7 * 64 + l];

#define EMSG(rr, dd, idx_)                                                    \
        if ((idx_) < e1) {                                                    \
            float z10 = a.x + hlo((rr).x), z20 = a.y + hhi((rr).x);           \
            float z11 = a.z + hlo((rr).y), z21 = a.w + hhi((rr).y);           \
            if ((dd) <= 6.34f) {                                              \
                int k0 = max(0, min(EDGE_DIM - NTAP, (int)ceilf((dd) * inv_s - 4.5f))); \
                const uint2* wr = WeL2 + k0 * 64 + l;                         \
                _Pragma("unroll")                                             \
                for (int t_ = 0; t_ < NTAP; t_++) {                           \
                    uint2 u = wr[t_ * 64];                                    \
                    float df = (dd) - (float)(k0 + t_) * sp_;                 \
                    float ee = __expf(coeff * df * df);                       \
                    z10 = fmaf(bflo(u.x), ee, z10); z20 = fmaf(bfhi(u.x), ee, z20); \
                    z11 = fmaf(bflo(u.y), ee, z11); z21 = fmaf(bfhi(u.y), ee, z21); \
                }                                                             \
            }                                                                 \
            acc0 += sigmoid_f(z10) * softplus_f(z20);                         \
            acc1 += sigmoid_f(z11) * softplus_f(z21);                         \
        }

#define COMPUTE(X, eb_)                                                       \
        EMSG(r##X##0, d##X##0, (eb_) + 0) EMSG(r##X##1, d##X##1, (eb_) + 1)   \
        EMSG(r##X##2, d##X##2, (eb_) + 2) EMSG(r##X##3, d##X##3, (eb_) + 3)   \
        EMSG(r##X##4, d##X##4, (eb_) + 4) EMSG(r##X##5, d##X##5, (eb_) + 5)   \
        EMSG(r##X##6, d##X##6, (eb_) + 6) EMSG(r##X##7, d##X##7, (eb_) + 7)

        // prologue: meta b0,b1 in flight; rows b0 issued
        MISSUE(A, e0)
        MISSUE(B, e0 + 8)
        __builtin_amdgcn_sched_barrier(0);
        SCALARIZE(A)
        RISSUE(A)
        __builtin_amdgcn_sched_barrier(0);
        int eb = e0;
        while (true) {
            // phase 1: compute b(k) from rA; prepare b(k+1) rows in rB; meta b(k+2) -> mA
            MISSUE(A, eb + 16)
            __builtin_amdgcn_sched_barrier(0);
            SCALARIZE(B)
            RISSUE(B)
            __builtin_amdgcn_sched_barrier(0);
            COMPUTE(A, eb)
            eb += 8; if (eb >= e1) break;
            // phase 2: mirror
            MISSUE(B, eb + 16)
            __builtin_amdgcn_sched_barrier(0);
            SCALARIZE(A)
            RISSUE(A)
            __builtin_amdgcn_sched_barrier(0);
            COMPUTE(B, eb)
            eb += 8; if (eb >= e1) break;
        }
#undef MISSUE
#undef SCAL1
#undef SCALARIZE
#undef RISSUE
#undef EMSG
#undef COMPUTE
    }

    // ---- fused layernorm + residual + softplus (wave-local) ----
    float s1 = acc0 + acc1;
    float s2 = acc0 * acc0 + acc1 * acc1;
#pragma unroll
    for (int off = 32; off > 0; off >>= 1) {
        s1 += __shfl_xor(s1, off);
        s2 += __shfl_xor(s2, off);
    }
    float mu = s1 * (1.0f / 128.0f);
    float var = s2 * (1.0f / 128.0f) - mu * mu;
    float rstd = rsqrtf(fmaxf(var, 0.f) + 1e-5f);
    float r0 = softplus_f((acc0 - mu) * rstd * gg.x + bv.x + xv.x);
    float r1 = softplus_f((acc1 - mu) * rstd * gg.y + bv.y + xv.y);
    *(float2*)&x[(size_t)node * 128 + 2 * l] = make_float2(r0, r1);
    __hip_bfloat16 h0 = (__hip_bfloat16)r0, h1 = (__hip_bfloat16)r1;
    unsigned pk = ((unsigned)*(unsigned short*)&h1 << 16) | (unsigned)*(unsigned short*)&h0;
    *(unsigned*)&xb[(size_t)node * 128 + 2 * l] = pk;
}

// ---------------------------------------------------------------- fused mean-pool + MLP head
__global__ void pool_head_kernel(const float* __restrict__ x, const int* __restrict__ gs,
                                 const float* __restrict__ cfc_w, const float* __restrict__ cfc_b,
                                 const float* __restrict__ fc_w, const float* __restrict__ fc_b,
                                 const float* __restrict__ out_w, const float* __restrict__ out_b,
                                 float* __restrict__ out) {
    int g = blockIdx.x, c = threadIdx.x;  // 128 threads
    int n0 = gs[g], n1 = gs[g + 1];
    float s = 0.f;
    for (int n = n0; n < n1; n++) s += x[(size_t)n * 128 + c];
    __shared__ float h[128], h2[128];
    h[c] = s / fmaxf((float)(n1 - n0), 1.0f);
    __syncthreads();
    float acc = cfc_b[c];
    for (int k = 0; k < 128; k++) acc = fmaf(h[k], cfc_w[k * 128 + c], acc);
    h2[c] = softplus_f(acc);
    __syncthreads();
    for (int l = 0; l < 2; l++) {
        const float* W = fc_w + l * 128 * 128;
        acc = fc_b[l * 128 + c];
        for (int k = 0; k < 128; k++) acc = fmaf(h2[k], W[k * 128 + c], acc);
        __syncthreads();
        h2[c] = softplus_f(acc);
        __syncthreads();
    }
    h[c] = h2[c] * out_w[c];
    __syncthreads();
    for (int off = 64; off > 0; off >>= 1) {
        if (c < off) h[c] += h[c + off];
        __syncthreads();
    }
    if (c == 0) out[g] = h[0] + out_b[0];
}

// ---------------------------------------------------------------- launcher
extern "C" void kernel_launch(void* const* d_in, const int* in_sizes, int n_in,
                              void* d_out, int out_size, void* d_ws, size_t ws_size,
                              hipStream_t stream) {
    const int*   z      = (const int*)d_in[0];
    const float* R      = (const float*)d_in[1];
    const int*   ei     = (const int*)d_in[2];
    const int*   batch  = (const int*)d_in[3];
    const float* emb    = (const float*)d_in[4];
    const float* emb_w  = (const float*)d_in[5];
    const float* emb_b  = (const float*)d_in[6];
    const float* conv_w = (const float*)d_in[7];
    const float* conv_b = (const float*)d_in[8];
    const float* ln_g   = (const float*)d_in[9];
    const float* ln_b   = (const float*)d_in[10];
    const float* cfc_w  = (const float*)d_in[11];
    const float* cfc_b  = (const float*)d_in[12];
    const float* fc_w   = (const float*)d_in[13];
    const float* fc_b   = (const float*)d_in[14];
    const float* out_w  = (const float*)d_in[15];
    const float* out_b  = (const float*)d_in[16];
    float* out = (float*)d_out;

    float* ws    = (float*)d_ws;
    float* x     = ws;                     // 6,400,000 floats
    float* agg   = x + 6400000;            // 6,400,000 (unused; layout kept)
    float* P1f   = agg + 6400000;          // 12,800,000 (packed fp32 pairs)
    _Float16* P2h = (_Float16*)(P1f + 12800000);  // 12,800,000 halves
    float* emf   = (float*)(P2h + 12800000);      // 1,600,000 (em float2)
    int* s_dst   = (int*)(emf + 1600000);  // 800,000 (unused; layout kept)
    int* row_ptr = s_dst + 800000;         // 50,004
    int* deg     = row_ptr + 50004;        // 50,000
    int* cnt2    = deg + 50000;            // 50,000
    int* bsum    = cnt2 + 50000;           // 64
    int* gs      = bsum + 64;              // 260
    unsigned* Wep        = (unsigned*)(gs + 260);              // 38,400 uints (packed We)
    short* WbB           = (short*)(Wep + 38400);              // 196,608 shorts
    __hip_bfloat16* xb   = (__hip_bfloat16*)(WbB + 196608);    // 6,400,000 bf16
    float2* em = (float2*)emf;

    hipMemsetAsync(deg, 0, (size_t)100000 * 4, stream);  // deg + cnt2
    deg_kernel<<<(N_EDGES + 255) / 256, 256, 0, stream>>>(ei, deg);
    int nsb = (N_NODES + SB - 1) / SB;  // 49
    scan1_kernel<<<nsb, SB, 0, stream>>>(deg, row_ptr, bsum);
    scan2_kernel<<<1, 64, 0, stream>>>(bsum, nsb);
    scan3_kernel<<<nsb, SB, 0, stream>>>(row_ptr, bsum);
    fill_kernel<<<(N_EDGES + 255) / 256, 256, 0, stream>>>(ei, R, row_ptr, cnt2, em);
    gb_kernel<<<(N_NODES + 256) / 256 + 1, 256, 0, stream>>>(batch, gs);
    wcvt_kernel<<<(3 * EDGE_DIM * 128 + 255) / 256, 256, 0, stream>>>(conv_w, Wep);
    wprep_kernel<<<(3 * 4 * 32 * 64 * 8 + 255) / 256, 256, 0, stream>>>(conv_w, WbB);

    embed_kernel<<<N_NODES / 8, 128, 0, stream>>>(z, emb, emb_w, emb_b, x, xb);
    for (int l = 0; l < 3; l++) {
        node_mfma_kernel<<<N_NODES / 16, 256, 0, stream>>>(xb, WbB + (size_t)l * 65536,
                                                           conv_b + l * 256, P1f, P2h);
        node_edge_ln_kernel<<<N_NODES / 8, 512, 0, stream>>>(
            row_ptr, em, (const float4*)P1f, (const uint2*)P2h,
            Wep + (size_t)l * EDGE_DIM * 128,
            ln_g + l * 128, ln_b + l * 128, x, xb);
    }
    pool_head_kernel<<<N_GRAPHS, 128, 0, stream>>>(x, gs, cfc_w, cfc_b, fc_w, fc_b,
                                                   out_w, out_b, out);
}